// Round 19
// baseline (388.884 us; speedup 1.0000x reference)
//
#include <hip/hip_runtime.h>

#define HH 384
#define WW 384
#define HWS (HH*WW)
#define NB 8
#define EPSV 1e-4f

typedef unsigned int u32;
typedef unsigned short u16;
typedef __attribute__((ext_vector_type(8))) short bf16x8;
typedef __attribute__((ext_vector_type(4))) float f32x4;

__device__ inline float bf2f(u16 h) { return __uint_as_float(((u32)h) << 16); }
__device__ inline u16 f2bf(float f) {
  u32 u = __float_as_uint(f);
  return (u16)((u + 0x7fffu + ((u >> 16) & 1u)) >> 16);
}
__device__ inline float fc4(const float4& v, int i) {
  return i == 0 ? v.x : i == 1 ? v.y : i == 2 ? v.z : v.w;
}

// ---------------- prep: zero sums, fold coef, weight transposes/packs (proven) ----------------
__global__ void k_prep(const float* __restrict__ adj_w,
                       const float* __restrict__ convH_w, const float* __restrict__ convH_b,
                       const float* __restrict__ convS_w, const float* __restrict__ convS_b,
                       const float* __restrict__ convRGB_w, const float* __restrict__ convRGB_b,
                       const float* __restrict__ gcm,
                       const float* __restrict__ c0_w, const float* __restrict__ wp0_w,
                       const float* __restrict__ c1_w, const float* __restrict__ wp1_w,
                       float* __restrict__ coef, float* __restrict__ c0t,
                       float* __restrict__ w0g, u32* __restrict__ wpk1,
                       u32* __restrict__ wpk2, float* __restrict__ sums) {
  int t = threadIdx.x;
  for (int i = t; i < NB * 16 * 9; i += 256) sums[i] = 0.f;
  for (int i = t; i < 432; i += 256) {
    int o = i & 15, rem = i >> 4;       // rem = c*9 + k9
    int c = rem / 9, k9 = rem - c * 9;
    c0t[i] = c0_w[(o * 3 + c) * 9 + k9];
    float s = 0.f;
    for (int j = 0; j < 3; j++) s += wp0_w[(o * 3 + j) * 9 + k9] * gcm[j * 3 + c];
    w0g[i] = s;
  }
  for (int i = t; i < 1280; i += 256) {
    int p = i >> 8;
    int rem = i & 255;
    int l = rem >> 2, wq = rem & 3;
    int tp = 2 * p + (l >> 5);
    int oc = l & 15;
    int ic0 = ((l >> 4) & 1) * 8 + wq * 2;
    u32 v1 = 0, v2 = 0;
    if (tp < 9) {
      v1 = f2bf(c1_w[(oc * 16 + ic0) * 9 + tp]);
      v2 = f2bf(c1_w[(oc * 16 + ic0 + 1) * 9 + tp]);
    }
    wpk1[i] = v1 | (v2 << 16);
    v1 = v2 = 0;
    if (tp < 9) {
      v1 = f2bf(wp1_w[(oc * 16 + ic0) * 9 + tp]);
      v2 = f2bf(wp1_w[(oc * 16 + ic0 + 1) * 9 + tp]);
    }
    wpk2[i] = v1 | (v2 << 16);
  }
  if (t < 64) {
    const float* a = adj_w + t * 64;
    float aH = 0, bH = 0, aS = 0, bS = 0, aR0 = 0, aR1 = 0, aR2 = 0, bR = 0;
    for (int i = 0; i < 16; i++) {
      aH += a[i] * convH_w[i];
      bH += a[i] * convH_b[i];
      aS += a[16 + i] * convS_w[i];
      bS += a[16 + i] * convS_b[i];
      float w = a[32 + i];
      aR0 += w * convRGB_w[i * 3 + 0];
      aR1 += w * convRGB_w[i * 3 + 1];
      aR2 += w * convRGB_w[i * 3 + 2];
      bR  += w * convRGB_b[i];
    }
    float* c = coef + t * 8;
    c[0] = aH; c[1] = bH; c[2] = aS; c[3] = bS;
    c[4] = aR0; c[5] = aR1; c[6] = aR2; c[7] = bR;
  }
}

// ---------------- scale stack: fp32 VALU, 32x16 tile, 4 blocks/CU, DETERMINISTIC ----------------
// Per-pixel math identical to R17; block totals written to partialsT (no atomics).
__global__ __launch_bounds__(256, 4) void k_stackV(
    const float* __restrict__ xin,
    const float* __restrict__ w0t, const float* __restrict__ b0,
    const float* __restrict__ w1,  const float* __restrict__ b1,
    float* __restrict__ partialsT) {
  __shared__ float xt[3][20][36];                 // 8640 B fp32 input halo
  __shared__ __align__(16) u16 s0[16 * 18 * 34];  // 19584 B layer0 out [ic][y][x]
  __shared__ float wl1[2304];                     // 9216 B layer1 weights
  __shared__ float red[64];

  const int tid = threadIdx.x;
  const int tx = tid & 15, ty = tid >> 4;
  const int b = blockIdx.z;
  const int bx = blockIdx.x * 32, by = blockIdx.y * 16;
  const float* xb = xin + (size_t)b * 3 * HWS;

  for (int i = tid; i < 2304; i += 256) {     // wl1[(c*9+k9)*16+o] = w1[o][c][k9]
    int o = i & 15, rem = i >> 4;
    int c = rem / 9, k9 = rem - c * 9;
    wl1[i] = w1[(o * 16 + c) * 9 + k9];
  }
  // stage input tile: rows by-2..by+17, cols bx-2..bx+33, zero-padded
  for (int i = tid; i < 3 * 20 * 36; i += 256) {
    int c = i / (20 * 36), r = i % (20 * 36);
    int yy = r / 36, xx = r - yy * 36;
    int gy = by + yy - 2, gx = bx + xx - 2;
    float v = 0.f;
    if ((u32)gy < HH && (u32)gx < WW) v = xb[(size_t)c * HWS + gy * WW + gx];
    xt[c][yy][xx] = v;
  }
  __syncthreads();

  // ---- stage 1: layer0 on 18x34 halo, silu ----
  for (int rnd = 0; rnd < 3; rnd++) {
    int p = tid + rnd * 256;
    if (p < 18 * 34) {
      int py = p / 34, pxh = p - py * 34;
      float a0[16];
#pragma unroll
      for (int o = 0; o < 16; o++) a0[o] = b0[o];
#pragma unroll 1
      for (int c = 0; c < 3; c++) {
#pragma unroll 1
        for (int ky = 0; ky < 3; ky++) {
#pragma unroll
          for (int kx = 0; kx < 3; kx++) {
            float xv = xt[c][py + ky][pxh + kx];
            const float* wr = &w0t[((c * 3 + ky) * 3 + kx) * 16];
#pragma unroll
            for (int o = 0; o < 16; o++) a0[o] = fmaf(xv, wr[o], a0[o]);
          }
        }
      }
      int oy = by + py - 1, ox = bx + pxh - 1;
      bool inside = ((u32)oy < HH) && ((u32)ox < WW);
      u16* sp = &s0[py * 34 + pxh];
#pragma unroll
      for (int o = 0; o < 16; o++) {
        float v = a0[o];
        v = v / (1.f + __expf(-v));      // silu
        sp[o * 18 * 34] = inside ? f2bf(v) : (u16)0;
      }
    }
  }
  __syncthreads();

  // ---- stage 2: layer1, 2 px per thread (vectorized LDS reads) ----
  float acc[2][16];
#pragma unroll
  for (int o = 0; o < 16; o++) {
    float bb = b1[o];
    acc[0][o] = bb; acc[1][o] = bb;
  }
  for (int c = 0; c < 16; c++) {
#pragma unroll
    for (int ky = 0; ky < 3; ky++) {
      const u16* rowp = &s0[(c * 18 + ty + ky) * 34 + tx * 2];
      u32 wa = *(const u32*)(rowp);      // u16 elems 0..1
      u32 wb = *(const u32*)(rowp + 2);  // u16 elems 2..3
      float v[4];
      v[0] = bf2f((u16)(wa & 0xffffu)); v[1] = bf2f((u16)(wa >> 16));
      v[2] = bf2f((u16)(wb & 0xffffu)); v[3] = bf2f((u16)(wb >> 16));
#pragma unroll
      for (int kx = 0; kx < 3; kx++) {
        const float* wr = &wl1[(c * 9 + ky * 3 + kx) * 16];
        float4 wA = *(const float4*)(wr);
        float4 wB = *(const float4*)(wr + 4);
        float4 wC = *(const float4*)(wr + 8);
        float4 wD = *(const float4*)(wr + 12);
#pragma unroll
        for (int px = 0; px < 2; px++) {
          float vv = v[px + kx];
          acc[px][0]  = fmaf(vv, wA.x, acc[px][0]);
          acc[px][1]  = fmaf(vv, wA.y, acc[px][1]);
          acc[px][2]  = fmaf(vv, wA.z, acc[px][2]);
          acc[px][3]  = fmaf(vv, wA.w, acc[px][3]);
          acc[px][4]  = fmaf(vv, wB.x, acc[px][4]);
          acc[px][5]  = fmaf(vv, wB.y, acc[px][5]);
          acc[px][6]  = fmaf(vv, wB.z, acc[px][6]);
          acc[px][7]  = fmaf(vv, wB.w, acc[px][7]);
          acc[px][8]  = fmaf(vv, wC.x, acc[px][8]);
          acc[px][9]  = fmaf(vv, wC.y, acc[px][9]);
          acc[px][10] = fmaf(vv, wC.z, acc[px][10]);
          acc[px][11] = fmaf(vv, wC.w, acc[px][11]);
          acc[px][12] = fmaf(vv, wD.x, acc[px][12]);
          acc[px][13] = fmaf(vv, wD.y, acc[px][13]);
          acc[px][14] = fmaf(vv, wD.z, acc[px][14]);
          acc[px][15] = fmaf(vv, wD.w, acc[px][15]);
        }
      }
    }
  }

  float tloc[16];
#pragma unroll
  for (int c = 0; c < 16; c++) {
    float s0v = acc[0][c] / (1.f + __expf(-acc[0][c]));
    float s1v = acc[1][c] / (1.f + __expf(-acc[1][c]));
    tloc[c] = s0v + s1v;
  }
  const int lane = tid & 63, wv_ = tid >> 6;
#pragma unroll
  for (int c = 0; c < 16; c++) {
    float t = tloc[c];
    t += __shfl_down(t, 32, 64);
    t += __shfl_down(t, 16, 64);
    t += __shfl_down(t, 8, 64);
    t += __shfl_down(t, 4, 64);
    t += __shfl_down(t, 2, 64);
    t += __shfl_down(t, 1, 64);
    if (lane == 0) red[c * 4 + wv_] = t;
  }
  __syncthreads();
  if (tid < 16) {
    int blk = blockIdx.y * gridDim.x + blockIdx.x;   // 0..287
    partialsT[((size_t)b * 288 + blk) * 16 + tid] =
        (red[tid * 4] + red[tid * 4 + 1]) + (red[tid * 4 + 2] + red[tid * 4 + 3]);
  }
}

// ---------------- border strips: recompute s1 on the 4 edges, deterministic writes ----------------
// grid = NB*4 blocks (b*4+strip), 128 threads, 3 px/thread.
__global__ __launch_bounds__(128) void k_border(
    const float* __restrict__ xin,
    const float* __restrict__ w0t, const float* __restrict__ b0,
    const float* __restrict__ w1,  const float* __restrict__ b1,
    float* __restrict__ sums) {
  __shared__ float wl1[2304];
  __shared__ float wl0[432];
  __shared__ float red2[2][16];
  const int tid = threadIdx.x;
  const int bs = blockIdx.x;
  const int b = bs >> 2, strip = bs & 3;
  const float* xb = xin + (size_t)b * 3 * HWS;
  for (int i = tid; i < 2304; i += 128) {
    int o = i & 15, rem = i >> 4;
    int c = rem / 9, k9 = rem - c * 9;
    wl1[i] = w1[(o * 16 + c) * 9 + k9];
  }
  for (int i = tid; i < 432; i += 128) wl0[i] = w0t[i];
  __syncthreads();

  float* S = sums + (size_t)b * 16 * 9;
  float strip_sum[16];
#pragma unroll
  for (int c = 0; c < 16; c++) strip_sum[c] = 0.f;

#pragma unroll 1
  for (int j = 0; j < 3; j++) {
    int idx = tid * 3 + j;            // 0..383
    int y, x;
    if (strip == 0)      { y = 0;      x = idx; }
    else if (strip == 1) { y = HH - 1; x = idx; }
    else if (strip == 2) { y = idx;    x = 0; }
    else                 { y = idx;    x = WW - 1; }

    float acc1[16];
#pragma unroll
    for (int o = 0; o < 16; o++) acc1[o] = b1[o];
#pragma unroll 1
    for (int ky = 0; ky < 3; ky++) {
#pragma unroll 1
      for (int kx = 0; kx < 3; kx++) {
        int py = y + ky - 1, px = x + kx - 1;
        float s0v[16];
        if ((u32)py < HH && (u32)px < WW) {
          float a0[16];
#pragma unroll
          for (int o = 0; o < 16; o++) a0[o] = b0[o];
#pragma unroll 1
          for (int ci = 0; ci < 3; ci++) {
#pragma unroll
            for (int k2 = 0; k2 < 3; k2++) {
#pragma unroll
              for (int k3 = 0; k3 < 3; k3++) {
                int gy = py + k2 - 1, gx = px + k3 - 1;
                float xv = ((u32)gy < HH && (u32)gx < WW)
                           ? xb[(size_t)ci * HWS + gy * WW + gx] : 0.f;
                const float* wr = &wl0[((ci * 3 + k2) * 3 + k3) * 16];
#pragma unroll
                for (int o = 0; o < 16; o++) a0[o] = fmaf(xv, wr[o], a0[o]);
              }
            }
          }
#pragma unroll
          for (int o = 0; o < 16; o++) {
            float sv = a0[o] / (1.f + __expf(-a0[o]));
            s0v[o] = bf2f(f2bf(sv));
          }
        } else {
#pragma unroll
          for (int o = 0; o < 16; o++) s0v[o] = 0.f;
        }
#pragma unroll
        for (int c = 0; c < 16; c++) {
          const float* wr = &wl1[(c * 9 + ky * 3 + kx) * 16];
          float v = s0v[c];
#pragma unroll
          for (int o = 0; o < 16; o++) acc1[o] = fmaf(v, wr[o], acc1[o]);
        }
      }
    }
    float s1s[16];
#pragma unroll
    for (int c = 0; c < 16; c++) {
      float vv = acc1[c];
      s1s[c] = vv / (1.f + __expf(-vv));
      strip_sum[c] += s1s[c];
    }
    // corner slots: single writer each (only row strips write corners)
    if (strip == 0 && x == 0) {
#pragma unroll
      for (int c = 0; c < 16; c++) S[c * 9 + 5] = s1s[c];
    }
    if (strip == 0 && x == WW - 1) {
#pragma unroll
      for (int c = 0; c < 16; c++) S[c * 9 + 6] = s1s[c];
    }
    if (strip == 1 && x == 0) {
#pragma unroll
      for (int c = 0; c < 16; c++) S[c * 9 + 7] = s1s[c];
    }
    if (strip == 1 && x == WW - 1) {
#pragma unroll
      for (int c = 0; c < 16; c++) S[c * 9 + 8] = s1s[c];
    }
  }

  const int lane = tid & 63, wv_ = tid >> 6;
#pragma unroll
  for (int c = 0; c < 16; c++) {
    float t = strip_sum[c];
#pragma unroll
    for (int m = 1; m <= 32; m <<= 1) t += __shfl_xor(t, m, 64);
    if (lane == 0) red2[wv_][c] = t;
  }
  __syncthreads();
  if (tid < 16) S[tid * 9 + 1 + strip] = red2[0][tid] + red2[1][tid];
}

// ---------------- wp stack: bf16 xt staging, 3 blocks/CU (R18, first-check proven) ----------------
__global__ __launch_bounds__(256, 3) void k_stackM(
    const float* __restrict__ xin,
    const float* __restrict__ w0t, const float* __restrict__ b0,
    const u32* __restrict__ wpk,  const float* __restrict__ b1,
    const float* __restrict__ wp2_w, const float* __restrict__ wp2_b,
    float* __restrict__ outw) {
  __shared__ u16 xt[3][20][68];
  __shared__ u16 s0[18 * 66 * 16];
  __shared__ float wl0[432];

  const int tid = threadIdx.x;
  const int b = blockIdx.z;
  const int bx = blockIdx.x * 64, by = blockIdx.y * 16;

  const float* xb = xin + (size_t)b * 3 * HWS;
  for (int i = tid; i < 432; i += 256) wl0[i] = w0t[i];
  for (int i = tid; i < 3 * 20 * 68; i += 256) {
    int c = i / (20 * 68), r = i % (20 * 68);
    int yy = r / 68, xx = r - yy * 68;
    int gy = by + yy - 2, gx = bx + xx - 2;
    float v = 0.f;
    if ((u32)gy < HH && (u32)gx < WW) v = xb[(size_t)c * HWS + gy * WW + gx];
    xt[c][yy][xx] = f2bf(v);
  }
  __syncthreads();

  for (int rnd = 0; rnd < 5; rnd++) {
    int p = tid + rnd * 256;
    if (p < 18 * 66) {
      int py = p / 66, pxh = p - py * 66;
      float a0[16];
#pragma unroll
      for (int o = 0; o < 16; o++) a0[o] = b0[o];
#pragma unroll 1
      for (int c = 0; c < 3; c++) {
#pragma unroll 1
        for (int ky = 0; ky < 3; ky++) {
#pragma unroll
          for (int kx = 0; kx < 3; kx++) {
            float xv = bf2f(xt[c][py + ky][pxh + kx]);
            const float* wr = &wl0[((c * 3 + ky) * 3 + kx) * 16];
#pragma unroll
            for (int o = 0; o < 16; o++) a0[o] = fmaf(xv, wr[o], a0[o]);
          }
        }
      }
      int oy = by + py - 1, ox = bx + pxh - 1;
      bool inside = ((u32)oy < HH) && ((u32)ox < WW);
      u32 base = (u32)p * 32;
      u32 sw = (u32)(((pxh >> 2) & 1) << 4);
      u32 pk[8];
#pragma unroll
      for (int q = 0; q < 8; q++) {
        float e0 = fmaxf(a0[2 * q], 0.f), e1 = fmaxf(a0[2 * q + 1], 0.f);
        pk[q] = inside ? ((u32)f2bf(e0) | ((u32)f2bf(e1) << 16)) : 0u;
      }
      *(uint4*)((char*)s0 + ((base +  0) ^ sw)) = make_uint4(pk[0], pk[1], pk[2], pk[3]);
      *(uint4*)((char*)s0 + ((base + 16) ^ sw)) = make_uint4(pk[4], pk[5], pk[6], pk[7]);
    }
  }
  __syncthreads();

  const int l = tid & 63;
  const int wv = tid >> 6;
  const int n = l & 15, icb = (l >> 4) & 1, tt = l >> 5;
  const int g = l >> 4;

  bf16x8 af[5];
#pragma unroll
  for (int p = 0; p < 5; p++) af[p] = *(const bf16x8*)(wpk + (p * 64 + l) * 4);

  f32x4 cinit;
#pragma unroll
  for (int j = 0; j < 4; j++) cinit[j] = b1[g * 4 + j];

  u32 aoff[5], xoff[5];
#pragma unroll
  for (int p = 0; p < 5; p++) {
    int tp = 2 * p + tt; if (tp > 8) tp = 8;
    int ky = tp / 3, kx = tp - ky * 3;
    aoff[p] = (u32)((ky * 66 + kx) * 32);
    xoff[p] = (u32)((((n + kx) >> 2) & 1) << 4);
  }

  float w2f[4][4], wp2b[4];
#pragma unroll
  for (int jj = 0; jj < 4; jj++) {
    wp2b[jj] = wp2_b[jj];
#pragma unroll
    for (int j = 0; j < 4; j++) w2f[jj][j] = wp2_w[jj * 16 + g * 4 + j];
  }

#pragma unroll 1
  for (int r = 0; r < 4; r++) {
    int yo = wv * 4 + r;
    int gy = by + yo;
#pragma unroll 2
    for (int s = 0; s < 4; s++) {
      int xseg = s * 16;
      u32 base = (u32)((yo * 66 + xseg + n) * 32 + icb * 16);
      f32x4 acc = cinit;
#pragma unroll
      for (int p = 0; p < 5; p++) {
        bf16x8 bf = *(const bf16x8*)((char*)s0 + ((base + aoff[p]) ^ xoff[p]));
        acc = __builtin_amdgcn_mfma_f32_16x16x32_bf16(af[p], bf, acc, 0, 0, 0);
      }
      float plg[4] = {0.f, 0.f, 0.f, 0.f};
#pragma unroll
      for (int j = 0; j < 4; j++) {
        float v = fmaxf(acc[j], 0.f);
#pragma unroll
        for (int jj = 0; jj < 4; jj++) plg[jj] = fmaf(v, w2f[jj][j], plg[jj]);
      }
      float lg[4];
#pragma unroll
      for (int jj = 0; jj < 4; jj++) {
        float v = plg[jj];
        v += __shfl_xor(v, 16, 64);
        v += __shfl_xor(v, 32, 64);
        lg[jj] = v + wp2b[jj];
      }
      float m4 = fmaxf(fmaxf(lg[0], lg[1]), fmaxf(lg[2], lg[3]));
      float e0 = __expf(lg[0] - m4), e1 = __expf(lg[1] - m4);
      float e2 = __expf(lg[2] - m4), e3_ = __expf(lg[3] - m4);
      float inv = 1.f / ((e0 + e1) + (e2 + e3_));
      if (g < 3) {
        float wv_ = (g == 0 ? e0 : (g == 1 ? e1 : e2)) * inv;
        outw[(size_t)b * 3 * HWS + (size_t)g * HWS + (size_t)gy * WW + bx + xseg + n] = wv_;
      }
    }
  }
}

// ---------------- scale finalize: fixed-order T reduce + border algebra + taps ----------------
__global__ void k_scaletaps(const float* __restrict__ partialsT,
                            const float* __restrict__ sums,
                            const float* __restrict__ c2_w, const float* __restrict__ c2_b,
                            float* __restrict__ taps) {
  int b = blockIdx.x, t = threadIdx.x;  // 64 threads
  __shared__ float red[16];
  if (t < 16) {
    const float* P = partialsT + (size_t)b * 288 * 16;
    float T = 0.f;
    for (int k = 0; k < 288; k++) T += P[k * 16 + t];   // fixed order
    const float* S = sums + ((size_t)b * 16 + t) * 9;
    float R0 = S[1], R1 = S[2], C0 = S[3], C1 = S[4];
    float a00 = S[5], a01 = S[6], a10 = S[7], a11 = S[8];
    float acc = 0.f;
    for (int ky = 0; ky < 3; ky++)
      for (int kx = 0; kx < 3; kx++) {
        float s = T;
        if (ky == 0) s -= R1;
        if (ky == 2) s -= R0;
        if (kx == 0) s -= C1;
        if (kx == 2) s -= C0;
        if (ky == 0 && kx == 0) s += a11;
        if (ky == 0 && kx == 2) s += a10;
        if (ky == 2 && kx == 0) s += a01;
        if (ky == 2 && kx == 2) s += a00;
        acc += c2_w[(t * 3 + ky) * 3 + kx] * s;
      }
    red[t] = acc;
  }
  __syncthreads();
  __shared__ float u[37];
  __shared__ float std_sh, f_sh;
  if (t == 0) {
    float m = 0.f;
    for (int c = 0; c < 16; c++) m += red[c];
    m = m / (float)HWS + c2_b[0];
    float sc = fminf(2.5f, fmaxf(-2.5f, m));
    std_sh = exp2f(sc);
    f_sh = ceilf(3.f * std_sh + 0.5f);
  }
  __syncthreads();
  if (t < 37) {
    float xv = (float)(t - 18);
    float q = xv / std_sh;
    u[t] = (fabsf(xv) <= f_sh) ? expf(-0.5f * q * q) : 0.f;
  }
  __syncthreads();
  if (t == 0) {
    float s1 = 0.f;
    for (int i = 0; i < 37; i++) s1 += u[i];
    float inv = 1.f / s1;
    for (int i = 0; i < 37; i++) taps[b * 37 + i] = u[i] * inv;
  }
}

// ---------------- separable 37-tap blur (gcm fused into H pass) ----------------
__global__ __launch_bounds__(128) void k_blurH(const float* __restrict__ x,
                                               const float* __restrict__ gcm,
                                               const float* __restrict__ taps,
                                               float* __restrict__ out) {
  __shared__ float row[3][164];
  __shared__ float tp[37];
  int b = blockIdx.z, y = blockIdx.y, x0 = blockIdx.x * 128, t = threadIdx.x;
  if (t < 37) tp[t] = taps[b * 37 + t];
  const float* xb = x + (size_t)b * 3 * HWS + (size_t)y * WW;
  float g0 = gcm[0], g1 = gcm[1], g2 = gcm[2];
  float g3 = gcm[3], g4 = gcm[4], g5 = gcm[5];
  float g6 = gcm[6], g7 = gcm[7], g8 = gcm[8];
  for (int idx = t; idx < 164; idx += 128) {
    int gx = x0 + idx - 18;
    bool ok = (u32)gx < WW;
    float v0 = ok ? xb[gx] : 0.f;
    float v1 = ok ? xb[HWS + gx] : 0.f;
    float v2 = ok ? xb[2 * HWS + gx] : 0.f;
    row[0][idx] = g0 * v0 + g1 * v1 + g2 * v2;
    row[1][idx] = g3 * v0 + g4 * v1 + g5 * v2;
    row[2][idx] = g6 * v0 + g7 * v1 + g8 * v2;
  }
  __syncthreads();
  float a0 = 0, a1 = 0, a2 = 0;
#pragma unroll
  for (int i = 0; i < 37; i++) {
    float w = tp[i];
    a0 = fmaf(w, row[0][t + i], a0);
    a1 = fmaf(w, row[1][t + i], a1);
    a2 = fmaf(w, row[2][t + i], a2);
  }
  float* ob = out + (size_t)b * 3 * HWS + (size_t)y * WW + x0 + t;
  ob[0] = a0; ob[HWS] = a1; ob[2 * HWS] = a2;
}

// 16 output rows per block; same per-output FMA order.
__global__ __launch_bounds__(128) void k_blurV(const float* __restrict__ in,
                                               const float* __restrict__ taps,
                                               float* __restrict__ out) {
  int img = blockIdx.z;                  // b*3 + c
  int y0 = blockIdx.y * 16;
  int xx = blockIdx.x * 128 + threadIdx.x;
  __shared__ float tp[37];
  if (threadIdx.x < 37) tp[threadIdx.x] = taps[(img / 3) * 37 + threadIdx.x];
  __syncthreads();
  const float* base = in + (size_t)img * HWS + xx;
  float acc[16];
#pragma unroll
  for (int k = 0; k < 16; k++) acc[k] = 0.f;
#pragma unroll
  for (int i = 0; i < 52; i++) {
    int gy = y0 + i - 18;
    float v = ((u32)gy < HH) ? base[(size_t)gy * WW] : 0.f;
#pragma unroll
    for (int k = 0; k < 16; k++) {
      int ti = i - k;
      if (ti >= 0 && ti < 37) acc[k] = fmaf(tp[ti], v, acc[k]);
    }
  }
  float* ob = out + (size_t)img * HWS + xx;
#pragma unroll
  for (int k = 0; k < 16; k++) ob[(size_t)(y0 + k) * WW] = acc[k];
}

// ---------------- final fusion (4 px/thread, float4 stores) ----------------
__global__ __launch_bounds__(256) void k_final(const float* __restrict__ x,
                                               const float* __restrict__ e3,
                                               const float* __restrict__ w012,
                                               const float* __restrict__ coef,
                                               const float* __restrict__ adj_b,
                                               float* __restrict__ out) {
  __shared__ float cf[576];
  int tid = threadIdx.x;
  for (int i = tid; i < 512; i += 256) cf[i] = coef[i];
  if (tid < 64) cf[512 + tid] = adj_b[tid];
  __syncthreads();
  int gi = blockIdx.x * 256 + tid;
  int pix = gi * 4;
  int b = pix / HWS, p = pix - b * HWS;

  const float* xb = x + (size_t)b * 3 * HWS + p;
  float4 X0 = *(const float4*)(xb);
  float4 X1 = *(const float4*)(xb + HWS);
  float4 X2 = *(const float4*)(xb + 2 * HWS);
  const float* eb = e3 + (size_t)b * 3 * HWS + p;
  float4 Ee  = *(const float4*)(eb);
  float4 Elv = *(const float4*)(eb + HWS);
  float4 Ell = *(const float4*)(eb + 2 * HWS);
  const float* wb = w012 + (size_t)b * 3 * HWS + p;
  float4 Wa = *(const float4*)(wb);
  float4 Wb = *(const float4*)(wb + HWS);
  float4 Wc = *(const float4*)(wb + 2 * HWS);

  float T[8][4];
#pragma unroll
  for (int px = 0; px < 4; px++) {
    float x0v = fc4(X0, px), x1v = fc4(X1, px), x2v = fc4(X2, px);
    int mx = 0;  float vm = x0v;
    if (x1v > vm) { mx = 1; vm = x1v; }
    if (x2v > vm) { mx = 2; vm = x2v; }
    int mxl = 0; vm = x0v;
    if (x1v >= vm) { mxl = 1; vm = x1v; }
    if (x2v >= vm) { mxl = 2; vm = x2v; }
    int mn = 0;  float vn = x0v;
    if (x1v < vn) { mn = 1; vn = x1v; }
    if (x2v < vn) { mn = 2; vn = x2v; }
    int mnl = 0; vn = x0v;
    if (x1v <= vn) { mnl = 1; vn = x1v; }
    if (x2v <= vn) { mnl = 2; vn = x2v; }
    float R0v = 0.5f * ((float)(mx == 0) + (float)(mxl == 0)) - 0.5f * ((float)(mn == 0) + (float)(mnl == 0));
    float R1v = 0.5f * ((float)(mx == 1) + (float)(mxl == 1)) - 0.5f * ((float)(mn == 1) + (float)(mnl == 1));
    float R2v = 0.5f * ((float)(mx == 2) + (float)(mxl == 2)) - 0.5f * ((float)(mn == 2) + (float)(mnl == 2));

    float Ev = fc4(Ee, px), El_ = fc4(Elv, px), Ell_ = fc4(Ell, px);
    float Hc = atanf(El_ / (Ell_ + EPSV));
    float Sc = logf((El_ * El_ + Ell_ * Ell_) / (Ev * Ev + EPSV) + EPSV);
    float w0 = fc4(Wa, px), w1 = fc4(Wb, px), w2 = fc4(Wc, px);
    T[0][px] = Hc * w0;  T[1][px] = w0;
    T[2][px] = Sc * w1;  T[3][px] = w1;
    T[4][px] = R0v * w2; T[5][px] = R1v * w2; T[6][px] = R2v * w2; T[7][px] = w2;
  }

  float* ob = out + (size_t)b * 64 * HWS + p;
#pragma unroll 4
  for (int o = 0; o < 64; o++) {
    float4 c0_ = *(const float4*)&cf[o * 8];
    float4 c1_ = *(const float4*)&cf[o * 8 + 4];
    float bb = cf[512 + o];
    float4 r;
    float rv[4];
#pragma unroll
    for (int px = 0; px < 4; px++) {
      float v = bb;
      v = fmaf(c0_.x, T[0][px], v); v = fmaf(c0_.y, T[1][px], v);
      v = fmaf(c0_.z, T[2][px], v); v = fmaf(c0_.w, T[3][px], v);
      v = fmaf(c1_.x, T[4][px], v); v = fmaf(c1_.y, T[5][px], v);
      v = fmaf(c1_.z, T[6][px], v); v = fmaf(c1_.w, T[7][px], v);
      rv[px] = v;
    }
    r.x = rv[0]; r.y = rv[1]; r.z = rv[2]; r.w = rv[3];
    *(float4*)(ob + (size_t)o * HWS) = r;
  }
}

// ---------------- host ----------------
extern "C" void kernel_launch(void* const* d_in, const int* in_sizes, int n_in,
                              void* d_out, int out_size, void* d_ws, size_t ws_size,
                              hipStream_t stream) {
  const float* x         = (const float*)d_in[0];
  const float* gcm       = (const float*)d_in[1];
  const float* convH_w   = (const float*)d_in[2];
  const float* convH_b   = (const float*)d_in[3];
  const float* convS_w   = (const float*)d_in[4];
  const float* convS_b   = (const float*)d_in[5];
  const float* convRGB_w = (const float*)d_in[6];
  const float* convRGB_b = (const float*)d_in[7];
  const float* convadj_w = (const float*)d_in[10];
  const float* convadj_b = (const float*)d_in[11];
  const float* c0_w  = (const float*)d_in[12];
  const float* c0_b  = (const float*)d_in[13];
  const float* c1_w  = (const float*)d_in[14];
  const float* c1_b  = (const float*)d_in[15];
  const float* c2_w  = (const float*)d_in[16];
  const float* c2_b  = (const float*)d_in[17];
  const float* wp0_w = (const float*)d_in[18];
  const float* wp0_b = (const float*)d_in[19];
  const float* wp1_w = (const float*)d_in[20];
  const float* wp1_b = (const float*)d_in[21];
  const float* wp2_w = (const float*)d_in[22];
  const float* wp2_b = (const float*)d_in[23];
  float* out = (float*)d_out;

  float* ws = (float*)d_ws;
  size_t off = 0;
  auto take = [&](size_t nf) { float* p = ws + off; off += nf; return p; };
  float* coef = take(512);
  float* c0t  = take(432);
  float* w0g  = take(432);
  u32*   wpk1 = (u32*)take(1280);
  u32*   wpk2 = (u32*)take(1280);
  float* sums = take((size_t)NB * 16 * 9);
  float* taps = take(320);
  float* partialsT = take((size_t)NB * 288 * 16);
  const size_t P3 = (size_t)NB * 3 * HWS;
  float* tmp3 = take(P3);
  float* e3   = take(P3);
  float* w012 = take(P3);

  k_prep<<<1, 256, 0, stream>>>(convadj_w, convH_w, convH_b, convS_w, convS_b,
                                convRGB_w, convRGB_b, gcm, c0_w, wp0_w,
                                c1_w, wp1_w, coef, c0t, w0g, wpk1, wpk2, sums);

  k_stackV<<<dim3(12, 24, NB), 256, 0, stream>>>(x, c0t, c0_b, c1_w, c1_b, partialsT);
  k_border<<<NB * 4, 128, 0, stream>>>(x, c0t, c0_b, c1_w, c1_b, sums);
  k_scaletaps<<<NB, 64, 0, stream>>>(partialsT, sums, c2_w, c2_b, taps);
  k_blurH<<<dim3(3, HH, NB), 128, 0, stream>>>(x, gcm, taps, tmp3);
  k_blurV<<<dim3(3, 24, NB * 3), 128, 0, stream>>>(tmp3, taps, e3);
  k_stackM<<<dim3(6, 24, NB), 256, 0, stream>>>(x, w0g, wp0_b, wpk2, wp1_b,
                                                wp2_w, wp2_b, w012);
  k_final<<<(NB * HWS / 4 + 255) / 256, 256, 0, stream>>>(x, e3, w012, coef, convadj_b, out);
}

// Round 20
// 306.437 us; speedup vs baseline: 1.2690x; 1.2690x over previous
//
#include <hip/hip_runtime.h>

#define HH 384
#define WW 384
#define HWS (HH*WW)
#define NB 8
#define EPSV 1e-4f

typedef unsigned int u32;
typedef unsigned short u16;
typedef __attribute__((ext_vector_type(8))) short bf16x8;
typedef __attribute__((ext_vector_type(4))) float f32x4;

__device__ inline float bf2f(u16 h) { return __uint_as_float(((u32)h) << 16); }
__device__ inline u16 f2bf(float f) {
  u32 u = __float_as_uint(f);
  return (u16)((u + 0x7fffu + ((u >> 16) & 1u)) >> 16);
}
__device__ inline float fc4(const float4& v, int i) {
  return i == 0 ? v.x : i == 1 ? v.y : i == 2 ? v.z : v.w;
}

// ---------------- prep: fold coef, weight transposes/packs (proven) ----------------
__global__ void k_prep(const float* __restrict__ adj_w,
                       const float* __restrict__ convH_w, const float* __restrict__ convH_b,
                       const float* __restrict__ convS_w, const float* __restrict__ convS_b,
                       const float* __restrict__ convRGB_w, const float* __restrict__ convRGB_b,
                       const float* __restrict__ gcm,
                       const float* __restrict__ c0_w, const float* __restrict__ wp0_w,
                       const float* __restrict__ c1_w, const float* __restrict__ wp1_w,
                       float* __restrict__ coef, float* __restrict__ c0t,
                       float* __restrict__ w0g, u32* __restrict__ wpk1,
                       u32* __restrict__ wpk2, float* __restrict__ sums) {
  int t = threadIdx.x;
  for (int i = t; i < NB * 16 * 9; i += 256) sums[i] = 0.f;
  for (int i = t; i < 432; i += 256) {
    int o = i & 15, rem = i >> 4;       // rem = c*9 + k9
    int c = rem / 9, k9 = rem - c * 9;
    c0t[i] = c0_w[(o * 3 + c) * 9 + k9];
    float s = 0.f;
    for (int j = 0; j < 3; j++) s += wp0_w[(o * 3 + j) * 9 + k9] * gcm[j * 3 + c];
    w0g[i] = s;
  }
  for (int i = t; i < 1280; i += 256) {
    int p = i >> 8;
    int rem = i & 255;
    int l = rem >> 2, wq = rem & 3;
    int tp = 2 * p + (l >> 5);
    int oc = l & 15;
    int ic0 = ((l >> 4) & 1) * 8 + wq * 2;
    u32 v1 = 0, v2 = 0;
    if (tp < 9) {
      v1 = f2bf(c1_w[(oc * 16 + ic0) * 9 + tp]);
      v2 = f2bf(c1_w[(oc * 16 + ic0 + 1) * 9 + tp]);
    }
    wpk1[i] = v1 | (v2 << 16);
    v1 = v2 = 0;
    if (tp < 9) {
      v1 = f2bf(wp1_w[(oc * 16 + ic0) * 9 + tp]);
      v2 = f2bf(wp1_w[(oc * 16 + ic0 + 1) * 9 + tp]);
    }
    wpk2[i] = v1 | (v2 << 16);
  }
  if (t < 64) {
    const float* a = adj_w + t * 64;
    float aH = 0, bH = 0, aS = 0, bS = 0, aR0 = 0, aR1 = 0, aR2 = 0, bR = 0;
    for (int i = 0; i < 16; i++) {
      aH += a[i] * convH_w[i];
      bH += a[i] * convH_b[i];
      aS += a[16 + i] * convS_w[i];
      bS += a[16 + i] * convS_b[i];
      float w = a[32 + i];
      aR0 += w * convRGB_w[i * 3 + 0];
      aR1 += w * convRGB_w[i * 3 + 1];
      aR2 += w * convRGB_w[i * 3 + 2];
      bR  += w * convRGB_b[i];
    }
    float* c = coef + t * 8;
    c[0] = aH; c[1] = bH; c[2] = aS; c[3] = bS;
    c[4] = aR0; c[5] = aR1; c[6] = aR2; c[7] = bR;
  }
}

// ---------------- scale stack: fp32 VALU, 32x16 tile, 4 blocks/CU, fully deterministic ----------------
// Per-pixel math identical to R17/R19. Interior totals -> partialsT; border strips reduced
// in-block via LDS fixed-order sums -> strips[b][72][16]; corners: single-thread writes.
__global__ __launch_bounds__(256, 4) void k_stackV(
    const float* __restrict__ xin,
    const float* __restrict__ w0t, const float* __restrict__ b0,
    const float* __restrict__ w1,  const float* __restrict__ b1,
    float* __restrict__ partialsT, float* __restrict__ strips,
    float* __restrict__ sums) {
  __shared__ float xt[3][20][36];                 // 8640 B fp32 input halo
  __shared__ __align__(16) u16 s0[16 * 18 * 34];  // 19584 B layer0 out [ic][y][x]
  __shared__ float wl1[2304];                     // 9216 B layer1 weights
  __shared__ float red[64];
  __shared__ float sbuf[16][17];                  // 1088 B strip reduce buffer

  const int tid = threadIdx.x;
  const int tx = tid & 15, ty = tid >> 4;
  const int b = blockIdx.z;
  const int bx = blockIdx.x * 32, by = blockIdx.y * 16;
  const float* xb = xin + (size_t)b * 3 * HWS;

  for (int i = tid; i < 2304; i += 256) {     // wl1[(c*9+k9)*16+o] = w1[o][c][k9]
    int o = i & 15, rem = i >> 4;
    int c = rem / 9, k9 = rem - c * 9;
    wl1[i] = w1[(o * 16 + c) * 9 + k9];
  }
  // stage input tile: rows by-2..by+17, cols bx-2..bx+33, zero-padded
  for (int i = tid; i < 3 * 20 * 36; i += 256) {
    int c = i / (20 * 36), r = i % (20 * 36);
    int yy = r / 36, xx = r - yy * 36;
    int gy = by + yy - 2, gx = bx + xx - 2;
    float v = 0.f;
    if ((u32)gy < HH && (u32)gx < WW) v = xb[(size_t)c * HWS + gy * WW + gx];
    xt[c][yy][xx] = v;
  }
  __syncthreads();

  // ---- stage 1: layer0 on 18x34 halo, silu ----
  for (int rnd = 0; rnd < 3; rnd++) {
    int p = tid + rnd * 256;
    if (p < 18 * 34) {
      int py = p / 34, pxh = p - py * 34;
      float a0[16];
#pragma unroll
      for (int o = 0; o < 16; o++) a0[o] = b0[o];
#pragma unroll 1
      for (int c = 0; c < 3; c++) {
#pragma unroll 1
        for (int ky = 0; ky < 3; ky++) {
#pragma unroll
          for (int kx = 0; kx < 3; kx++) {
            float xv = xt[c][py + ky][pxh + kx];
            const float* wr = &w0t[((c * 3 + ky) * 3 + kx) * 16];
#pragma unroll
            for (int o = 0; o < 16; o++) a0[o] = fmaf(xv, wr[o], a0[o]);
          }
        }
      }
      int oy = by + py - 1, ox = bx + pxh - 1;
      bool inside = ((u32)oy < HH) && ((u32)ox < WW);
      u16* sp = &s0[py * 34 + pxh];
#pragma unroll
      for (int o = 0; o < 16; o++) {
        float v = a0[o];
        v = v / (1.f + __expf(-v));      // silu
        sp[o * 18 * 34] = inside ? f2bf(v) : (u16)0;
      }
    }
  }
  __syncthreads();

  // ---- stage 2: layer1, 2 px per thread (vectorized LDS reads) ----
  float acc[2][16];
#pragma unroll
  for (int o = 0; o < 16; o++) {
    float bb = b1[o];
    acc[0][o] = bb; acc[1][o] = bb;
  }
  for (int c = 0; c < 16; c++) {
#pragma unroll
    for (int ky = 0; ky < 3; ky++) {
      const u16* rowp = &s0[(c * 18 + ty + ky) * 34 + tx * 2];
      u32 wa = *(const u32*)(rowp);      // u16 elems 0..1
      u32 wb = *(const u32*)(rowp + 2);  // u16 elems 2..3
      float v[4];
      v[0] = bf2f((u16)(wa & 0xffffu)); v[1] = bf2f((u16)(wa >> 16));
      v[2] = bf2f((u16)(wb & 0xffffu)); v[3] = bf2f((u16)(wb >> 16));
#pragma unroll
      for (int kx = 0; kx < 3; kx++) {
        const float* wr = &wl1[(c * 9 + ky * 3 + kx) * 16];
        float4 wA = *(const float4*)(wr);
        float4 wB = *(const float4*)(wr + 4);
        float4 wC = *(const float4*)(wr + 8);
        float4 wD = *(const float4*)(wr + 12);
#pragma unroll
        for (int px = 0; px < 2; px++) {
          float vv = v[px + kx];
          acc[px][0]  = fmaf(vv, wA.x, acc[px][0]);
          acc[px][1]  = fmaf(vv, wA.y, acc[px][1]);
          acc[px][2]  = fmaf(vv, wA.z, acc[px][2]);
          acc[px][3]  = fmaf(vv, wA.w, acc[px][3]);
          acc[px][4]  = fmaf(vv, wB.x, acc[px][4]);
          acc[px][5]  = fmaf(vv, wB.y, acc[px][5]);
          acc[px][6]  = fmaf(vv, wB.z, acc[px][6]);
          acc[px][7]  = fmaf(vv, wB.w, acc[px][7]);
          acc[px][8]  = fmaf(vv, wC.x, acc[px][8]);
          acc[px][9]  = fmaf(vv, wC.y, acc[px][9]);
          acc[px][10] = fmaf(vv, wC.z, acc[px][10]);
          acc[px][11] = fmaf(vv, wC.w, acc[px][11]);
          acc[px][12] = fmaf(vv, wD.x, acc[px][12]);
          acc[px][13] = fmaf(vv, wD.y, acc[px][13]);
          acc[px][14] = fmaf(vv, wD.z, acc[px][14]);
          acc[px][15] = fmaf(vv, wD.w, acc[px][15]);
        }
      }
    }
  }

  float tloc[16];
#pragma unroll
  for (int c = 0; c < 16; c++) {
    float s0v = acc[0][c] / (1.f + __expf(-acc[0][c]));
    float s1v = acc[1][c] / (1.f + __expf(-acc[1][c]));
    tloc[c] = s0v + s1v;
  }
  const int lane = tid & 63, wv_ = tid >> 6;
#pragma unroll
  for (int c = 0; c < 16; c++) {
    float t = tloc[c];
    t += __shfl_down(t, 32, 64);
    t += __shfl_down(t, 16, 64);
    t += __shfl_down(t, 8, 64);
    t += __shfl_down(t, 4, 64);
    t += __shfl_down(t, 2, 64);
    t += __shfl_down(t, 1, 64);
    if (lane == 0) red[c * 4 + wv_] = t;
  }
  __syncthreads();
  if (tid < 16) {
    int blk = blockIdx.y * gridDim.x + blockIdx.x;   // 0..287
    partialsT[((size_t)b * 288 + blk) * 16 + tid] =
        (red[tid * 4] + red[tid * 4 + 1]) + (red[tid * 4 + 2] + red[tid * 4 + 3]);
  }

  // ---- border strip partials (block-uniform conditions; fixed-order LDS sums) ----
  float* Sb = strips + (size_t)b * 72 * 16;
  if (blockIdx.y == 0) {                 // row y=0: threads ty==0, contribution = tloc
    __syncthreads();
    if (ty == 0) {
#pragma unroll
      for (int c = 0; c < 16; c++) sbuf[tx][c] = tloc[c];
    }
    __syncthreads();
    if (tid < 16) {
      float s = 0.f;
      for (int k = 0; k < 16; k++) s += sbuf[k][tid];
      Sb[(0 + blockIdx.x) * 16 + tid] = s;
    }
  }
  if (blockIdx.y == 23) {                // row y=383: threads ty==15
    __syncthreads();
    if (ty == 15) {
#pragma unroll
      for (int c = 0; c < 16; c++) sbuf[tx][c] = tloc[c];
    }
    __syncthreads();
    if (tid < 16) {
      float s = 0.f;
      for (int k = 0; k < 16; k++) s += sbuf[k][tid];
      Sb[(12 + blockIdx.x) * 16 + tid] = s;
    }
  }
  if (blockIdx.x == 0) {                 // col x=0: threads tx==0, contribution = silu(acc[0])
    __syncthreads();
    if (tx == 0) {
#pragma unroll
      for (int c = 0; c < 16; c++) sbuf[ty][c] = acc[0][c] / (1.f + __expf(-acc[0][c]));
    }
    __syncthreads();
    if (tid < 16) {
      float s = 0.f;
      for (int k = 0; k < 16; k++) s += sbuf[k][tid];
      Sb[(24 + blockIdx.y) * 16 + tid] = s;
    }
  }
  if (blockIdx.x == 11) {                // col x=383: threads tx==15, contribution = silu(acc[1])
    __syncthreads();
    if (tx == 15) {
#pragma unroll
      for (int c = 0; c < 16; c++) sbuf[ty][c] = acc[1][c] / (1.f + __expf(-acc[1][c]));
    }
    __syncthreads();
    if (tid < 16) {
      float s = 0.f;
      for (int k = 0; k < 16; k++) s += sbuf[k][tid];
      Sb[(48 + blockIdx.y) * 16 + tid] = s;
    }
  }
  // corners: single writer each
  float* S = sums + (size_t)b * 16 * 9;
  if (blockIdx.y == 0 && blockIdx.x == 0 && tid == 0) {
#pragma unroll
    for (int c = 0; c < 16; c++) S[c * 9 + 5] = acc[0][c] / (1.f + __expf(-acc[0][c]));
  }
  if (blockIdx.y == 0 && blockIdx.x == 11 && tid == 15) {
#pragma unroll
    for (int c = 0; c < 16; c++) S[c * 9 + 6] = acc[1][c] / (1.f + __expf(-acc[1][c]));
  }
  if (blockIdx.y == 23 && blockIdx.x == 0 && tid == 240) {
#pragma unroll
    for (int c = 0; c < 16; c++) S[c * 9 + 7] = acc[0][c] / (1.f + __expf(-acc[0][c]));
  }
  if (blockIdx.y == 23 && blockIdx.x == 11 && tid == 255) {
#pragma unroll
    for (int c = 0; c < 16; c++) S[c * 9 + 8] = acc[1][c] / (1.f + __expf(-acc[1][c]));
  }
}

// ---------------- wp stack: bf16 xt staging, 3 blocks/CU (proven) ----------------
__global__ __launch_bounds__(256, 3) void k_stackM(
    const float* __restrict__ xin,
    const float* __restrict__ w0t, const float* __restrict__ b0,
    const u32* __restrict__ wpk,  const float* __restrict__ b1,
    const float* __restrict__ wp2_w, const float* __restrict__ wp2_b,
    float* __restrict__ outw) {
  __shared__ u16 xt[3][20][68];
  __shared__ u16 s0[18 * 66 * 16];
  __shared__ float wl0[432];

  const int tid = threadIdx.x;
  const int b = blockIdx.z;
  const int bx = blockIdx.x * 64, by = blockIdx.y * 16;

  const float* xb = xin + (size_t)b * 3 * HWS;
  for (int i = tid; i < 432; i += 256) wl0[i] = w0t[i];
  for (int i = tid; i < 3 * 20 * 68; i += 256) {
    int c = i / (20 * 68), r = i % (20 * 68);
    int yy = r / 68, xx = r - yy * 68;
    int gy = by + yy - 2, gx = bx + xx - 2;
    float v = 0.f;
    if ((u32)gy < HH && (u32)gx < WW) v = xb[(size_t)c * HWS + gy * WW + gx];
    xt[c][yy][xx] = f2bf(v);
  }
  __syncthreads();

  for (int rnd = 0; rnd < 5; rnd++) {
    int p = tid + rnd * 256;
    if (p < 18 * 66) {
      int py = p / 66, pxh = p - py * 66;
      float a0[16];
#pragma unroll
      for (int o = 0; o < 16; o++) a0[o] = b0[o];
#pragma unroll 1
      for (int c = 0; c < 3; c++) {
#pragma unroll 1
        for (int ky = 0; ky < 3; ky++) {
#pragma unroll
          for (int kx = 0; kx < 3; kx++) {
            float xv = bf2f(xt[c][py + ky][pxh + kx]);
            const float* wr = &wl0[((c * 3 + ky) * 3 + kx) * 16];
#pragma unroll
            for (int o = 0; o < 16; o++) a0[o] = fmaf(xv, wr[o], a0[o]);
          }
        }
      }
      int oy = by + py - 1, ox = bx + pxh - 1;
      bool inside = ((u32)oy < HH) && ((u32)ox < WW);
      u32 base = (u32)p * 32;
      u32 sw = (u32)(((pxh >> 2) & 1) << 4);
      u32 pk[8];
#pragma unroll
      for (int q = 0; q < 8; q++) {
        float e0 = fmaxf(a0[2 * q], 0.f), e1 = fmaxf(a0[2 * q + 1], 0.f);
        pk[q] = inside ? ((u32)f2bf(e0) | ((u32)f2bf(e1) << 16)) : 0u;
      }
      *(uint4*)((char*)s0 + ((base +  0) ^ sw)) = make_uint4(pk[0], pk[1], pk[2], pk[3]);
      *(uint4*)((char*)s0 + ((base + 16) ^ sw)) = make_uint4(pk[4], pk[5], pk[6], pk[7]);
    }
  }
  __syncthreads();

  const int l = tid & 63;
  const int wv = tid >> 6;
  const int n = l & 15, icb = (l >> 4) & 1, tt = l >> 5;
  const int g = l >> 4;

  bf16x8 af[5];
#pragma unroll
  for (int p = 0; p < 5; p++) af[p] = *(const bf16x8*)(wpk + (p * 64 + l) * 4);

  f32x4 cinit;
#pragma unroll
  for (int j = 0; j < 4; j++) cinit[j] = b1[g * 4 + j];

  u32 aoff[5], xoff[5];
#pragma unroll
  for (int p = 0; p < 5; p++) {
    int tp = 2 * p + tt; if (tp > 8) tp = 8;
    int ky = tp / 3, kx = tp - ky * 3;
    aoff[p] = (u32)((ky * 66 + kx) * 32);
    xoff[p] = (u32)((((n + kx) >> 2) & 1) << 4);
  }

  float w2f[4][4], wp2b[4];
#pragma unroll
  for (int jj = 0; jj < 4; jj++) {
    wp2b[jj] = wp2_b[jj];
#pragma unroll
    for (int j = 0; j < 4; j++) w2f[jj][j] = wp2_w[jj * 16 + g * 4 + j];
  }

#pragma unroll 1
  for (int r = 0; r < 4; r++) {
    int yo = wv * 4 + r;
    int gy = by + yo;
#pragma unroll 2
    for (int s = 0; s < 4; s++) {
      int xseg = s * 16;
      u32 base = (u32)((yo * 66 + xseg + n) * 32 + icb * 16);
      f32x4 acc = cinit;
#pragma unroll
      for (int p = 0; p < 5; p++) {
        bf16x8 bf = *(const bf16x8*)((char*)s0 + ((base + aoff[p]) ^ xoff[p]));
        acc = __builtin_amdgcn_mfma_f32_16x16x32_bf16(af[p], bf, acc, 0, 0, 0);
      }
      float plg[4] = {0.f, 0.f, 0.f, 0.f};
#pragma unroll
      for (int j = 0; j < 4; j++) {
        float v = fmaxf(acc[j], 0.f);
#pragma unroll
        for (int jj = 0; jj < 4; jj++) plg[jj] = fmaf(v, w2f[jj][j], plg[jj]);
      }
      float lg[4];
#pragma unroll
      for (int jj = 0; jj < 4; jj++) {
        float v = plg[jj];
        v += __shfl_xor(v, 16, 64);
        v += __shfl_xor(v, 32, 64);
        lg[jj] = v + wp2b[jj];
      }
      float m4 = fmaxf(fmaxf(lg[0], lg[1]), fmaxf(lg[2], lg[3]));
      float e0 = __expf(lg[0] - m4), e1 = __expf(lg[1] - m4);
      float e2 = __expf(lg[2] - m4), e3_ = __expf(lg[3] - m4);
      float inv = 1.f / ((e0 + e1) + (e2 + e3_));
      if (g < 3) {
        float wv_ = (g == 0 ? e0 : (g == 1 ? e1 : e2)) * inv;
        outw[(size_t)b * 3 * HWS + (size_t)g * HWS + (size_t)gy * WW + bx + xseg + n] = wv_;
      }
    }
  }
}

// ---------------- scale finalize: fixed-order reductions + border algebra + taps ----------------
__global__ void k_scaletaps(const float* __restrict__ partialsT,
                            const float* __restrict__ strips,
                            const float* __restrict__ sums,
                            const float* __restrict__ c2_w, const float* __restrict__ c2_b,
                            float* __restrict__ taps) {
  int b = blockIdx.x, t = threadIdx.x;  // 64 threads
  __shared__ float red[16];
  if (t < 16) {
    const float* P = partialsT + (size_t)b * 288 * 16;
    float T = 0.f;
    for (int k = 0; k < 288; k++) T += P[k * 16 + t];   // fixed order
    const float* Sb = strips + (size_t)b * 72 * 16;
    float R0 = 0.f, R1 = 0.f, C0 = 0.f, C1 = 0.f;
    for (int k = 0; k < 12; k++) R0 += Sb[(0 + k) * 16 + t];
    for (int k = 0; k < 12; k++) R1 += Sb[(12 + k) * 16 + t];
    for (int k = 0; k < 24; k++) C0 += Sb[(24 + k) * 16 + t];
    for (int k = 0; k < 24; k++) C1 += Sb[(48 + k) * 16 + t];
    const float* S = sums + ((size_t)b * 16 + t) * 9;
    float a00 = S[5], a01 = S[6], a10 = S[7], a11 = S[8];
    float acc = 0.f;
    for (int ky = 0; ky < 3; ky++)
      for (int kx = 0; kx < 3; kx++) {
        float s = T;
        if (ky == 0) s -= R1;
        if (ky == 2) s -= R0;
        if (kx == 0) s -= C1;
        if (kx == 2) s -= C0;
        if (ky == 0 && kx == 0) s += a11;
        if (ky == 0 && kx == 2) s += a10;
        if (ky == 2 && kx == 0) s += a01;
        if (ky == 2 && kx == 2) s += a00;
        acc += c2_w[(t * 3 + ky) * 3 + kx] * s;
      }
    red[t] = acc;
  }
  __syncthreads();
  __shared__ float u[37];
  __shared__ float std_sh, f_sh;
  if (t == 0) {
    float m = 0.f;
    for (int c = 0; c < 16; c++) m += red[c];
    m = m / (float)HWS + c2_b[0];
    float sc = fminf(2.5f, fmaxf(-2.5f, m));
    std_sh = exp2f(sc);
    f_sh = ceilf(3.f * std_sh + 0.5f);
  }
  __syncthreads();
  if (t < 37) {
    float xv = (float)(t - 18);
    float q = xv / std_sh;
    u[t] = (fabsf(xv) <= f_sh) ? expf(-0.5f * q * q) : 0.f;
  }
  __syncthreads();
  if (t == 0) {
    float s1 = 0.f;
    for (int i = 0; i < 37; i++) s1 += u[i];
    float inv = 1.f / s1;
    for (int i = 0; i < 37; i++) taps[b * 37 + i] = u[i] * inv;
  }
}

// ---------------- separable 37-tap blur (gcm fused into H pass) ----------------
__global__ __launch_bounds__(128) void k_blurH(const float* __restrict__ x,
                                               const float* __restrict__ gcm,
                                               const float* __restrict__ taps,
                                               float* __restrict__ out) {
  __shared__ float row[3][164];
  __shared__ float tp[37];
  int b = blockIdx.z, y = blockIdx.y, x0 = blockIdx.x * 128, t = threadIdx.x;
  if (t < 37) tp[t] = taps[b * 37 + t];
  const float* xb = x + (size_t)b * 3 * HWS + (size_t)y * WW;
  float g0 = gcm[0], g1 = gcm[1], g2 = gcm[2];
  float g3 = gcm[3], g4 = gcm[4], g5 = gcm[5];
  float g6 = gcm[6], g7 = gcm[7], g8 = gcm[8];
  for (int idx = t; idx < 164; idx += 128) {
    int gx = x0 + idx - 18;
    bool ok = (u32)gx < WW;
    float v0 = ok ? xb[gx] : 0.f;
    float v1 = ok ? xb[HWS + gx] : 0.f;
    float v2 = ok ? xb[2 * HWS + gx] : 0.f;
    row[0][idx] = g0 * v0 + g1 * v1 + g2 * v2;
    row[1][idx] = g3 * v0 + g4 * v1 + g5 * v2;
    row[2][idx] = g6 * v0 + g7 * v1 + g8 * v2;
  }
  __syncthreads();
  float a0 = 0, a1 = 0, a2 = 0;
#pragma unroll
  for (int i = 0; i < 37; i++) {
    float w = tp[i];
    a0 = fmaf(w, row[0][t + i], a0);
    a1 = fmaf(w, row[1][t + i], a1);
    a2 = fmaf(w, row[2][t + i], a2);
  }
  float* ob = out + (size_t)b * 3 * HWS + (size_t)y * WW + x0 + t;
  ob[0] = a0; ob[HWS] = a1; ob[2 * HWS] = a2;
}

// 16 output rows per block; same per-output FMA order.
__global__ __launch_bounds__(128) void k_blurV(const float* __restrict__ in,
                                               const float* __restrict__ taps,
                                               float* __restrict__ out) {
  int img = blockIdx.z;                  // b*3 + c
  int y0 = blockIdx.y * 16;
  int xx = blockIdx.x * 128 + threadIdx.x;
  __shared__ float tp[37];
  if (threadIdx.x < 37) tp[threadIdx.x] = taps[(img / 3) * 37 + threadIdx.x];
  __syncthreads();
  const float* base = in + (size_t)img * HWS + xx;
  float acc[16];
#pragma unroll
  for (int k = 0; k < 16; k++) acc[k] = 0.f;
#pragma unroll
  for (int i = 0; i < 52; i++) {
    int gy = y0 + i - 18;
    float v = ((u32)gy < HH) ? base[(size_t)gy * WW] : 0.f;
#pragma unroll
    for (int k = 0; k < 16; k++) {
      int ti = i - k;
      if (ti >= 0 && ti < 37) acc[k] = fmaf(tp[ti], v, acc[k]);
    }
  }
  float* ob = out + (size_t)img * HWS + xx;
#pragma unroll
  for (int k = 0; k < 16; k++) ob[(size_t)(y0 + k) * WW] = acc[k];
}

// ---------------- final fusion (4 px/thread, float4 stores) ----------------
__global__ __launch_bounds__(256) void k_final(const float* __restrict__ x,
                                               const float* __restrict__ e3,
                                               const float* __restrict__ w012,
                                               const float* __restrict__ coef,
                                               const float* __restrict__ adj_b,
                                               float* __restrict__ out) {
  __shared__ float cf[576];
  int tid = threadIdx.x;
  for (int i = tid; i < 512; i += 256) cf[i] = coef[i];
  if (tid < 64) cf[512 + tid] = adj_b[tid];
  __syncthreads();
  int gi = blockIdx.x * 256 + tid;
  int pix = gi * 4;
  int b = pix / HWS, p = pix - b * HWS;

  const float* xb = x + (size_t)b * 3 * HWS + p;
  float4 X0 = *(const float4*)(xb);
  float4 X1 = *(const float4*)(xb + HWS);
  float4 X2 = *(const float4*)(xb + 2 * HWS);
  const float* eb = e3 + (size_t)b * 3 * HWS + p;
  float4 Ee  = *(const float4*)(eb);
  float4 Elv = *(const float4*)(eb + HWS);
  float4 Ell = *(const float4*)(eb + 2 * HWS);
  const float* wb = w012 + (size_t)b * 3 * HWS + p;
  float4 Wa = *(const float4*)(wb);
  float4 Wb = *(const float4*)(wb + HWS);
  float4 Wc = *(const float4*)(wb + 2 * HWS);

  float T[8][4];
#pragma unroll
  for (int px = 0; px < 4; px++) {
    float x0v = fc4(X0, px), x1v = fc4(X1, px), x2v = fc4(X2, px);
    int mx = 0;  float vm = x0v;
    if (x1v > vm) { mx = 1; vm = x1v; }
    if (x2v > vm) { mx = 2; vm = x2v; }
    int mxl = 0; vm = x0v;
    if (x1v >= vm) { mxl = 1; vm = x1v; }
    if (x2v >= vm) { mxl = 2; vm = x2v; }
    int mn = 0;  float vn = x0v;
    if (x1v < vn) { mn = 1; vn = x1v; }
    if (x2v < vn) { mn = 2; vn = x2v; }
    int mnl = 0; vn = x0v;
    if (x1v <= vn) { mnl = 1; vn = x1v; }
    if (x2v <= vn) { mnl = 2; vn = x2v; }
    float R0v = 0.5f * ((float)(mx == 0) + (float)(mxl == 0)) - 0.5f * ((float)(mn == 0) + (float)(mnl == 0));
    float R1v = 0.5f * ((float)(mx == 1) + (float)(mxl == 1)) - 0.5f * ((float)(mn == 1) + (float)(mnl == 1));
    float R2v = 0.5f * ((float)(mx == 2) + (float)(mxl == 2)) - 0.5f * ((float)(mn == 2) + (float)(mnl == 2));

    float Ev = fc4(Ee, px), El_ = fc4(Elv, px), Ell_ = fc4(Ell, px);
    float Hc = atanf(El_ / (Ell_ + EPSV));
    float Sc = logf((El_ * El_ + Ell_ * Ell_) / (Ev * Ev + EPSV) + EPSV);
    float w0 = fc4(Wa, px), w1 = fc4(Wb, px), w2 = fc4(Wc, px);
    T[0][px] = Hc * w0;  T[1][px] = w0;
    T[2][px] = Sc * w1;  T[3][px] = w1;
    T[4][px] = R0v * w2; T[5][px] = R1v * w2; T[6][px] = R2v * w2; T[7][px] = w2;
  }

  float* ob = out + (size_t)b * 64 * HWS + p;
#pragma unroll 4
  for (int o = 0; o < 64; o++) {
    float4 c0_ = *(const float4*)&cf[o * 8];
    float4 c1_ = *(const float4*)&cf[o * 8 + 4];
    float bb = cf[512 + o];
    float4 r;
    float rv[4];
#pragma unroll
    for (int px = 0; px < 4; px++) {
      float v = bb;
      v = fmaf(c0_.x, T[0][px], v); v = fmaf(c0_.y, T[1][px], v);
      v = fmaf(c0_.z, T[2][px], v); v = fmaf(c0_.w, T[3][px], v);
      v = fmaf(c1_.x, T[4][px], v); v = fmaf(c1_.y, T[5][px], v);
      v = fmaf(c1_.z, T[6][px], v); v = fmaf(c1_.w, T[7][px], v);
      rv[px] = v;
    }
    r.x = rv[0]; r.y = rv[1]; r.z = rv[2]; r.w = rv[3];
    *(float4*)(ob + (size_t)o * HWS) = r;
  }
}

// ---------------- host ----------------
extern "C" void kernel_launch(void* const* d_in, const int* in_sizes, int n_in,
                              void* d_out, int out_size, void* d_ws, size_t ws_size,
                              hipStream_t stream) {
  const float* x         = (const float*)d_in[0];
  const float* gcm       = (const float*)d_in[1];
  const float* convH_w   = (const float*)d_in[2];
  const float* convH_b   = (const float*)d_in[3];
  const float* convS_w   = (const float*)d_in[4];
  const float* convS_b   = (const float*)d_in[5];
  const float* convRGB_w = (const float*)d_in[6];
  const float* convRGB_b = (const float*)d_in[7];
  const float* convadj_w = (const float*)d_in[10];
  const float* convadj_b = (const float*)d_in[11];
  const float* c0_w  = (const float*)d_in[12];
  const float* c0_b  = (const float*)d_in[13];
  const float* c1_w  = (const float*)d_in[14];
  const float* c1_b  = (const float*)d_in[15];
  const float* c2_w  = (const float*)d_in[16];
  const float* c2_b  = (const float*)d_in[17];
  const float* wp0_w = (const float*)d_in[18];
  const float* wp0_b = (const float*)d_in[19];
  const float* wp1_w = (const float*)d_in[20];
  const float* wp1_b = (const float*)d_in[21];
  const float* wp2_w = (const float*)d_in[22];
  const float* wp2_b = (const float*)d_in[23];
  float* out = (float*)d_out;

  float* ws = (float*)d_ws;
  size_t off = 0;
  auto take = [&](size_t nf) { float* p = ws + off; off += nf; return p; };
  float* coef = take(512);
  float* c0t  = take(432);
  float* w0g  = take(432);
  u32*   wpk1 = (u32*)take(1280);
  u32*   wpk2 = (u32*)take(1280);
  float* sums = take((size_t)NB * 16 * 9);
  float* taps = take(320);
  float* partialsT = take((size_t)NB * 288 * 16);
  float* strips    = take((size_t)NB * 72 * 16);
  const size_t P3 = (size_t)NB * 3 * HWS;
  float* tmp3 = take(P3);
  float* e3   = take(P3);
  float* w012 = take(P3);

  k_prep<<<1, 256, 0, stream>>>(convadj_w, convH_w, convH_b, convS_w, convS_b,
                                convRGB_w, convRGB_b, gcm, c0_w, wp0_w,
                                c1_w, wp1_w, coef, c0t, w0g, wpk1, wpk2, sums);

  k_stackV<<<dim3(12, 24, NB), 256, 0, stream>>>(x, c0t, c0_b, c1_w, c1_b,
                                                 partialsT, strips, sums);
  k_scaletaps<<<NB, 64, 0, stream>>>(partialsT, strips, sums, c2_w, c2_b, taps);
  k_blurH<<<dim3(3, HH, NB), 128, 0, stream>>>(x, gcm, taps, tmp3);
  k_blurV<<<dim3(3, 24, NB * 3), 128, 0, stream>>>(tmp3, taps, e3);
  k_stackM<<<dim3(6, 24, NB), 256, 0, stream>>>(x, w0g, wp0_b, wpk2, wp1_b,
                                                wp2_w, wp2_b, w012);
  k_final<<<(NB * HWS / 4 + 255) / 256, 256, 0, stream>>>(x, e3, w012, coef, convadj_b, out);
}